// Round 5
// baseline (281.617 us; speedup 1.0000x reference)
//
#include <hip/hip_runtime.h>

#define NN 100000      // nodes
#define NE 1600000     // edges
#define NBKT 782       // ceil(NN/128) buckets of 128 nodes
#define CAPB 2432      // per-bucket capacity (mean 2046, +8.5 sigma)
#define CHUNK 2048     // edges per bin block
#define NBIN_BLK ((NE + CHUNK - 1) / CHUNK)   // 782
#define BPT 4          // buckets per thread in bin scan (256*4 >= 782)

// d_ws layout (4B units):
//   gcur  @ 0    : NBKT ints
//   pairs @ 1024 : NBKT*CAPB uints  (~7.6 MB total)

__global__ void zero_cur(int* __restrict__ gcur) {
    int i = blockIdx.x * blockDim.x + threadIdx.x;
    if (i < NBKT) gcur[i] = 0;
}

// LDS-aggregated binning; wave-cooperative coalesced run copy-out.
__global__ __launch_bounds__(256) void bin_kernel(
        const int* __restrict__ src, const int* __restrict__ dst,
        int* __restrict__ gcur, unsigned* __restrict__ pairs) {
    __shared__ unsigned stage[CHUNK];   // 8 KB
    __shared__ int hist[NBKT];
    __shared__ int bbase[NBKT];
    __shared__ int curs[NBKT];
    __shared__ int gbase[NBKT];
    __shared__ int tsum[256];

    const int tid = threadIdx.x;
    const int e0 = blockIdx.x * CHUNK;
    const int n = min(CHUNK, NE - e0);

    for (int b = tid; b < NBKT; b += 256) hist[b] = 0;
    __syncthreads();

    for (int i = tid; i < n; i += 256)
        atomicAdd(&hist[dst[e0 + i] >> 7], 1);
    __syncthreads();

    // blocked exclusive scan: thread t owns buckets [t*BPT, t*BPT+BPT)
    int local[BPT];
    int s = 0;
    for (int k = 0; k < BPT; ++k) {
        const int b = tid * BPT + k;
        const int v = (b < NBKT) ? hist[b] : 0;
        local[k] = s;
        s += v;
    }
    tsum[tid] = s;
    __syncthreads();
    for (int st = 1; st < 256; st <<= 1) {
        int t = (tid >= st) ? tsum[tid - st] : 0;
        __syncthreads();
        tsum[tid] += t;
        __syncthreads();
    }
    const int tbase = tsum[tid] - s;
    for (int k = 0; k < BPT; ++k) {
        const int b = tid * BPT + k;
        if (b < NBKT) { bbase[b] = tbase + local[k]; curs[b] = 0; }
    }
    __syncthreads();

    // scatter pairs into LDS stage, grouped by bucket
    for (int i = tid; i < n; i += 256) {
        const int d = dst[e0 + i];
        const int sv = src[e0 + i];
        const int b = d >> 7;
        const int pos = bbase[b] + atomicAdd(&curs[b], 1);
        stage[pos] = ((unsigned)sv << 7) | (unsigned)(d & 127);
    }
    __syncthreads();

    // reserve global space: one atomic per non-empty (block,bucket)
    for (int b = tid; b < NBKT; b += 256) {
        const int c = curs[b];
        gbase[b] = (c > 0) ? atomicAdd(&gcur[b], c) : 0;
    }
    __syncthreads();

    // wave-cooperative coalesced copy of each bucket's run
    const int sub = tid >> 5;          // 8 subgroups of 32
    const int lane = tid & 31;
    for (int b = sub; b < NBKT; b += 8) {
        const int c = curs[b];
        if (c == 0) continue;
        const int lb = bbase[b];
        const int gb = gbase[b];
        unsigned* gp = pairs + (size_t)b * CAPB;
        for (int j = lane; j < c; j += 32) {
            const int gpos = gb + j;
            if (gpos < CAPB) gp[gpos] = stage[lb + j];
        }
    }
}

// one block of 512 per bucket: LDS sub-CSR + fused gather/finalize.
// 16 subgroups of 32 lanes; lane owns one float4 (full 512B row per edge).
__global__ __launch_bounds__(512) void sort_gather(
        const float4* __restrict__ feats4,
        const int* __restrict__ gcur,
        const unsigned* __restrict__ pairs,
        float4* __restrict__ out4) {
    __shared__ unsigned pairs_s[CAPB];   // 9728 B
    __shared__ int idx_s[CAPB];          // 9728 B
    __shared__ int hist[128];
    __shared__ int offs[128];
    __shared__ int curs[128];

    const int b = blockIdx.x;
    const int node0 = b << 7;
    const int nNodes = min(128, NN - node0);
    const int tid = threadIdx.x;

    int cnt = gcur[b];
    if (cnt > CAPB) cnt = CAPB;

    if (tid < 128) hist[tid] = 0;
    __syncthreads();

    const unsigned* gp = pairs + (size_t)b * CAPB;
    for (int i = tid; i < cnt; i += 512) {
        const unsigned p = gp[i];
        pairs_s[i] = p;
        atomicAdd(&hist[p & 127], 1);
    }
    __syncthreads();

    if (tid < 128) curs[tid] = hist[tid];
    __syncthreads();
    for (int st = 1; st < 128; st <<= 1) {
        int t = (tid < 128 && tid >= st) ? curs[tid - st] : 0;
        __syncthreads();
        if (tid < 128) curs[tid] += t;
        __syncthreads();
    }
    if (tid < 128) {
        const int ex = curs[tid] - hist[tid];
        offs[tid] = ex;
        curs[tid] = ex;
    }
    __syncthreads();

    for (int i = tid; i < cnt; i += 512) {
        const unsigned p = pairs_s[i];
        const int pos = atomicAdd(&curs[p & 127], 1);
        idx_s[pos] = (int)(p >> 7);
    }
    __syncthreads();

    const int lane = tid & 31;         // float4 column in [0,32)
    const int sub = tid >> 5;          // 0..15
    for (int dl = sub; dl < nNodes; dl += 16) {
        const int start = offs[dl];
        const int deg = hist[dl];
        float4 acc = make_float4(0.f, 0.f, 0.f, 0.f);
        int j = 0;
        for (; j + 3 < deg; j += 4) {
            const int s0 = idx_s[start + j + 0];
            const int s1 = idx_s[start + j + 1];
            const int s2 = idx_s[start + j + 2];
            const int s3 = idx_s[start + j + 3];
            const float4 v0 = feats4[(size_t)s0 * 32 + lane];
            const float4 v1 = feats4[(size_t)s1 * 32 + lane];
            const float4 v2 = feats4[(size_t)s2 * 32 + lane];
            const float4 v3 = feats4[(size_t)s3 * 32 + lane];
            acc.x += v0.x + v1.x + v2.x + v3.x;
            acc.y += v0.y + v1.y + v2.y + v3.y;
            acc.z += v0.z + v1.z + v2.z + v3.z;
            acc.w += v0.w + v1.w + v2.w + v3.w;
        }
        for (; j < deg; ++j) {
            const float4 v = feats4[(size_t)idx_s[start + j] * 32 + lane];
            acc.x += v.x; acc.y += v.y; acc.z += v.z; acc.w += v.w;
        }
        const int node = node0 + dl;
        const float inv = 0.5f / fmaxf((float)deg, 1.0f);
        const float4 f = feats4[(size_t)node * 32 + lane];
        float4 r;
        r.x = 0.5f * f.x + inv * acc.x;
        r.y = 0.5f * f.y + inv * acc.y;
        r.z = 0.5f * f.z + inv * acc.z;
        r.w = 0.5f * f.w + inv * acc.w;
        out4[(size_t)node * 32 + lane] = r;
    }
}

extern "C" void kernel_launch(void* const* d_in, const int* in_sizes, int n_in,
                              void* d_out, int out_size, void* d_ws, size_t ws_size,
                              hipStream_t stream) {
    const float* feats = (const float*)d_in[0];
    const int*   src   = (const int*)d_in[1];
    const int*   dst   = (const int*)d_in[2];
    float* out = (float*)d_out;

    int*      gcur  = (int*)d_ws;
    unsigned* pairs = (unsigned*)d_ws + 1024;

    zero_cur<<<(NBKT + 255) / 256, 256, 0, stream>>>(gcur);
    bin_kernel<<<NBIN_BLK, 256, 0, stream>>>(src, dst, gcur, pairs);
    sort_gather<<<NBKT, 512, 0, stream>>>(
        (const float4*)feats, gcur, pairs, (float4*)out);
}

// Round 6
// 253.569 us; speedup vs baseline: 1.1106x; 1.1106x over previous
//
#include <hip/hip_runtime.h>

#define NN 100000
#define NE 1600000
#define NBKT 782            // fine buckets of 128 nodes
#define CAPB 2432           // fine-bucket capacity (mean 2046 + 8.5 sigma)
#define NSB 25              // super-buckets of 4096 nodes
#define CAPS 67584          // super-bucket capacity (mean 65536 + 8 sigma)
#define CH1 4096            // edges per bin1 block
#define NB1 ((NE + CH1 - 1) / CH1)            // 391
#define SLICES 16           // bin2 blocks per super-bucket
#define MAXSL ((CAPS + SLICES - 1) / SLICES)  // 4224

// d_ws layout (4B words):
//   gcur1  @ 0       : 25 counters padded x16 (400 words, 1 line each)
//   gcur   @ 512     : NBKT ints
//   pairs1 @ 2048    : NSB*CAPS  = 1,689,600
//   pairs  @ 1691648 : NBKT*CAPB = 1,901,824   (total ~14.4 MB)

__global__ void zero_kernel(int* __restrict__ ws) {
    int i = blockIdx.x * blockDim.x + threadIdx.x;
    if (i < 512 + NBKT) ws[i] = 0;
}

// ---- pass 1: edges -> 25 super-buckets (payload = src<<12 | dst&4095) ----
__global__ __launch_bounds__(256) void bin1_kernel(
        const int* __restrict__ src, const int* __restrict__ dst,
        int* __restrict__ gcur1, unsigned* __restrict__ pairs1) {
    __shared__ unsigned stage[CH1];     // 16 KB
    __shared__ int hist[NSB], bbase[NSB], curs[NSB], gbase[NSB];
    const int tid = threadIdx.x;
    const int e0 = blockIdx.x * CH1;
    const int n = min(CH1, NE - e0);

    if (tid < NSB) hist[tid] = 0;
    __syncthreads();
    for (int i = tid; i < n; i += 256) atomicAdd(&hist[dst[e0 + i] >> 12], 1);
    __syncthreads();
    if (tid == 0) { int s = 0; for (int b = 0; b < NSB; ++b) { bbase[b] = s; s += hist[b]; } }
    __syncthreads();
    if (tid < NSB) curs[tid] = 0;
    __syncthreads();
    for (int i = tid; i < n; i += 256) {
        const int d = dst[e0 + i];
        const int sv = src[e0 + i];
        const int b = d >> 12;
        const int pos = bbase[b] + atomicAdd(&curs[b], 1);
        stage[pos] = ((unsigned)sv << 12) | (unsigned)(d & 4095);
    }
    __syncthreads();
    if (tid < NSB) gbase[tid] = curs[tid] ? atomicAdd(&gcur1[tid * 16], curs[tid]) : 0;
    __syncthreads();
    // coalesced copy-out: one wave per super-bucket run (avg 164 words)
    const int w = tid >> 6, lane = tid & 63;
    for (int b = w; b < NSB; b += 4) {
        const int c = curs[b], lb = bbase[b], gb = gbase[b];
        unsigned* gp = pairs1 + (size_t)b * CAPS;
        for (int j = lane; j < c; j += 64) {
            const int gpos = gb + j;
            if (gpos < CAPS) gp[gpos] = stage[lb + j];
        }
    }
}

// ---- pass 2: super-bucket slices -> 32 fine buckets (payload = src<<7 | dst&127) ----
__global__ __launch_bounds__(256) void bin2_kernel(
        const int* __restrict__ gcur1, const unsigned* __restrict__ pairs1,
        int* __restrict__ gcur, unsigned* __restrict__ pairs) {
    __shared__ unsigned stage[MAXSL];   // 16.9 KB
    __shared__ int hist[32], bbase[32], curs[32], gbase[32];
    const int sb = blockIdx.x >> 4;     // / SLICES
    const int sl = blockIdx.x & (SLICES - 1);
    const int tid = threadIdx.x;

    const int cnt = min(gcur1[sb * 16], CAPS);
    const int per = (cnt + SLICES - 1) / SLICES;
    const int i0 = sl * per;
    const int n = max(0, min(per, cnt - i0));

    if (tid < 32) hist[tid] = 0;
    __syncthreads();
    const unsigned* sp = pairs1 + (size_t)sb * CAPS + i0;
    for (int i = tid; i < n; i += 256) atomicAdd(&hist[(sp[i] & 4095) >> 7], 1);
    __syncthreads();
    if (tid == 0) { int s = 0; for (int b = 0; b < 32; ++b) { bbase[b] = s; s += hist[b]; } }
    __syncthreads();
    if (tid < 32) curs[tid] = 0;
    __syncthreads();
    for (int i = tid; i < n; i += 256) {
        const unsigned p = sp[i];
        const int f = (p & 4095) >> 7;
        const int pos = bbase[f] + atomicAdd(&curs[f], 1);
        stage[pos] = ((p >> 12) << 7) | (p & 127);
    }
    __syncthreads();
    if (tid < 32) {
        const int fb = sb * 32 + tid;
        gbase[tid] = (curs[tid] > 0 && fb < NBKT) ? atomicAdd(&gcur[fb], curs[tid]) : 0;
    }
    __syncthreads();
    // coalesced copy-out: one wave per fine-bucket run (avg ~128 words)
    const int w = tid >> 6, lane = tid & 63;
    for (int f = w; f < 32; f += 4) {
        const int fb = sb * 32 + f;
        if (fb >= NBKT) continue;
        const int c = curs[f], lb = bbase[f], gb = gbase[f];
        unsigned* gp = pairs + (size_t)fb * CAPB;
        for (int j = lane; j < c; j += 64) {
            const int gpos = gb + j;
            if (gpos < CAPB) gp[gpos] = stage[lb + j];
        }
    }
}

// ---- fused LDS sub-CSR build + gather/finalize (r3-best config) ----
__global__ __launch_bounds__(256) void sort_gather(
        const float2* __restrict__ feats2,
        const int* __restrict__ gcur,
        const unsigned* __restrict__ pairs,
        float2* __restrict__ out2) {
    __shared__ unsigned pairs_s[CAPB];   // 9.7 KB
    __shared__ int idx_s[CAPB];          // 9.7 KB
    __shared__ int hist[128], offs[128], curs[128];

    const int b = blockIdx.x;
    const int node0 = b << 7;
    const int nNodes = min(128, NN - node0);
    const int tid = threadIdx.x;

    const int cnt = min(gcur[b], CAPB);

    if (tid < 128) hist[tid] = 0;
    __syncthreads();

    const unsigned* gp = pairs + (size_t)b * CAPB;
    for (int i = tid; i < cnt; i += 256) {
        const unsigned p = gp[i];
        pairs_s[i] = p;
        atomicAdd(&hist[p & 127], 1);
    }
    __syncthreads();

    if (tid < 128) curs[tid] = hist[tid];
    __syncthreads();
    for (int st = 1; st < 128; st <<= 1) {
        int t = (tid < 128 && tid >= st) ? curs[tid - st] : 0;
        __syncthreads();
        if (tid < 128) curs[tid] += t;
        __syncthreads();
    }
    if (tid < 128) {
        const int ex = curs[tid] - hist[tid];
        offs[tid] = ex;
        curs[tid] = ex;
    }
    __syncthreads();

    for (int i = tid; i < cnt; i += 256) {
        const unsigned p = pairs_s[i];
        const int pos = atomicAdd(&curs[p & 127], 1);
        idx_s[pos] = (int)(p >> 7);
    }
    __syncthreads();

    const int lane = tid & 63;   // float2 column in [0,64)
    const int w = tid >> 6;      // wave 0..3
    for (int dl = w; dl < nNodes; dl += 4) {
        const int start = offs[dl];
        const int deg = hist[dl];
        float2 acc = make_float2(0.f, 0.f);
        int j = 0;
        for (; j + 3 < deg; j += 4) {
            const int s0 = idx_s[start + j + 0];
            const int s1 = idx_s[start + j + 1];
            const int s2 = idx_s[start + j + 2];
            const int s3 = idx_s[start + j + 3];
            const float2 v0 = feats2[(size_t)s0 * 64 + lane];
            const float2 v1 = feats2[(size_t)s1 * 64 + lane];
            const float2 v2 = feats2[(size_t)s2 * 64 + lane];
            const float2 v3 = feats2[(size_t)s3 * 64 + lane];
            acc.x += v0.x + v1.x + v2.x + v3.x;
            acc.y += v0.y + v1.y + v2.y + v3.y;
        }
        for (; j < deg; ++j) {
            const float2 v = feats2[(size_t)idx_s[start + j] * 64 + lane];
            acc.x += v.x; acc.y += v.y;
        }
        const int node = node0 + dl;
        const float inv = 0.5f / fmaxf((float)deg, 1.0f);
        const float2 f = feats2[(size_t)node * 64 + lane];
        out2[(size_t)node * 64 + lane] =
            make_float2(0.5f * f.x + inv * acc.x, 0.5f * f.y + inv * acc.y);
    }
}

extern "C" void kernel_launch(void* const* d_in, const int* in_sizes, int n_in,
                              void* d_out, int out_size, void* d_ws, size_t ws_size,
                              hipStream_t stream) {
    const float* feats = (const float*)d_in[0];
    const int*   src   = (const int*)d_in[1];
    const int*   dst   = (const int*)d_in[2];
    float* out = (float*)d_out;

    int*      ws_i   = (int*)d_ws;
    int*      gcur1  = ws_i;                 // padded x16
    int*      gcur   = ws_i + 512;
    unsigned* pairs1 = (unsigned*)ws_i + 2048;
    unsigned* pairs  = (unsigned*)ws_i + 2048 + NSB * CAPS;

    zero_kernel<<<6, 256, 0, stream>>>(ws_i);
    bin1_kernel<<<NB1, 256, 0, stream>>>(src, dst, gcur1, pairs1);
    bin2_kernel<<<NSB * SLICES, 256, 0, stream>>>(gcur1, pairs1, gcur, pairs);
    sort_gather<<<NBKT, 256, 0, stream>>>(
        (const float2*)feats, gcur, pairs, (float2*)out);
}